// Round 3
// baseline (712.074 us; speedup 1.0000x reference)
//
#include <hip/hip_runtime.h>
#include <hip/hip_bf16.h>

#define BB 16
#define CC 384
#define HH 56
#define WW 56
#define PLANE (HH*WW)
#define NHW (BB*PLANE)
// SW=108 floats -> b128 granule stride 27. Per 16-lane phase (4 rows x 4
// colgroups): granule mod 8 = {0,3,6,1} + {0,4} = all 8 classes x2 -> b128
// conflict-free. (Round-2 conflicts came from compiler b32 fallback at
// VGPR=64, where 4k-float strides give 8-way conflicts for ANY k.)
#define SW 108
#define ROWS 86    // 15 + 56 + 15
#define COL0 16    // center col offset (16B-aligned; halo needs only 15)
#define ROW0 15
#define ST3 61     // kernel3 LDS stride (odd)

// ---------------- Kernel 1: 31x31 depthwise conv + stats (+5x5 stats) ----------------
// amdgpu_waves_per_eu(4,4): pin occupancy target to exactly 4 waves/EU
// (= what LDS 37.2KB allows anyway) -> VGPR cap 128 and scheduler permission
// to use them, so win[48]+acc[16] stay live and ds_read_b128 can be formed.
// Round 2 showed __launch_bounds__(256,4) alone leaves VGPR_Count=64.
__global__ __launch_bounds__(256)
__attribute__((amdgpu_waves_per_eu(4, 4)))
void conv_large_k(
    const float* __restrict__ x, const float* __restrict__ wL,
    const float* __restrict__ wS,
    __hip_bfloat16* __restrict__ yL, float* __restrict__ stats)
{
    __shared__ float in_s[ROWS * SW];   // 86*108*4 = 37152 B
    __shared__ float red_s[16];         // 4 waves x 4 stats

    const int bid = blockIdx.x;
    const int c   = bid % CC;
    const int tid = threadIdx.x;

    // weight base pointers -- block-uniform => compiler scalarizes loads (s_load)
    const float* __restrict__ wrow = wL + c * 961;
    const float* __restrict__ w2   = wS + c * 25;

    // zero LDS input buffer (9288 floats, multiple of 4)
    for (int i = tid * 4; i < ROWS * SW; i += 256 * 4) {
        *(float4*)&in_s[i] = make_float4(0.f, 0.f, 0.f, 0.f);
    }
    __syncthreads();

    // load plane center: 784 float4 (56%4==0 so no row crossing)
    const float4* xp = (const float4*)(x + (size_t)bid * PLANE);
    for (int t = tid; t < PLANE / 4; t += 256) {
        int r  = t / (WW / 4);
        int c4 = (t % (WW / 4)) * 4;
        *(float4*)&in_s[(r + ROW0) * SW + COL0 + c4] = xp[t];
    }
    __syncthreads();

    const int y  = tid >> 2;       // output row
    const int x0 = (tid & 3) << 4; // output col start (0,16,32,48)

    float sL = 0.f, sL2 = 0.f, sS = 0.f, sS2 = 0.f;

    if (y < HH) {
        const int nvalid = (x0 + 16 <= WW) ? 16 : (WW - x0); // 16 or 8
        // ---- large conv: 16 outputs, register sliding window ----
        float acc[16];
        #pragma unroll
        for (int j = 0; j < 16; ++j) acc[j] = 0.f;

        #pragma unroll 1
        for (int ky = 0; ky < 31; ++ky) {
            const float* irow = &in_s[(y + ky) * SW + x0]; // 16B aligned
            float win[48];
            #pragma unroll
            for (int t2 = 0; t2 < 12; ++t2)
                *(float4*)&win[t2 * 4] = *(const float4*)&irow[t2 * 4];
            const float* wr = wrow + ky * 31;   // uniform -> SGPR loads
            #pragma unroll
            for (int kx = 0; kx < 31; ++kx) {
                float wv = wr[kx];
                #pragma unroll
                for (int j = 0; j < 16; ++j)
                    acc[j] = fmaf(win[j + kx + 1], wv, acc[j]); // pcol = x0+j+kx-15+COL0
            }
        }

        // store yL as bf16 (8B-aligned ushort4 packs; nvalid is 8 or 16)
        __hip_bfloat16* yrow = yL + (size_t)bid * PLANE + y * WW + x0;
        #pragma unroll
        for (int j = 0; j < 16; j += 4) {
            if (j < nvalid) {
                union { ushort4 u4; __hip_bfloat16 h[4]; } pk;
                #pragma unroll
                for (int q = 0; q < 4; ++q) {
                    float v = acc[j + q];
                    pk.h[q] = __float2bfloat16(v);
                    sL += v; sL2 += v * v;
                }
                *(ushort4*)(yrow + j) = pk.u4;
            }
        }

        // ---- small conv (stats only; recomputed in kernel 3) ----
        // aligned window: read 24 floats (6 x float4) from x0+12; need x0+14..x0+33
        float accS[16];
        #pragma unroll
        for (int j = 0; j < 16; ++j) accS[j] = 0.f;
        #pragma unroll 1
        for (int ky2 = 0; ky2 < 5; ++ky2) {
            const float* irow = &in_s[(y + ky2 + 13) * SW + x0 + 12]; // 16B aligned
            float win2[24];
            #pragma unroll
            for (int t2 = 0; t2 < 6; ++t2)
                *(float4*)&win2[t2 * 4] = *(const float4*)&irow[t2 * 4];
            #pragma unroll
            for (int kx2 = 0; kx2 < 5; ++kx2) {
                float wv = w2[ky2 * 5 + kx2];   // uniform -> SGPR
                #pragma unroll
                for (int j = 0; j < 16; ++j)
                    accS[j] = fmaf(win2[j + kx2 + 2], wv, accS[j]); // pcol = x0+j+kx2-2+COL0
            }
        }
        #pragma unroll
        for (int j = 0; j < 16; ++j) {
            if (j < nvalid) { float v = accS[j]; sS += v; sS2 += v * v; }
        }
    }

    // ---- block reduce 4 stats -> atomics ----
    #pragma unroll
    for (int off = 32; off > 0; off >>= 1) {
        sL  += __shfl_down(sL,  off);
        sL2 += __shfl_down(sL2, off);
        sS  += __shfl_down(sS,  off);
        sS2 += __shfl_down(sS2, off);
    }
    const int wid  = tid >> 6;
    const int lane = tid & 63;
    if (lane == 0) {
        red_s[wid * 4 + 0] = sL;  red_s[wid * 4 + 1] = sL2;
        red_s[wid * 4 + 2] = sS;  red_s[wid * 4 + 3] = sS2;
    }
    __syncthreads();
    if (tid == 0) {
        float a = 0.f, b = 0.f, d = 0.f, e = 0.f;
        #pragma unroll
        for (int w2i = 0; w2i < 4; ++w2i) {
            a += red_s[w2i * 4 + 0]; b += red_s[w2i * 4 + 1];
            d += red_s[w2i * 4 + 2]; e += red_s[w2i * 4 + 3];
        }
        atomicAdd(&stats[c],        a);
        atomicAdd(&stats[384 + c],  b);
        atomicAdd(&stats[768 + c],  d);
        atomicAdd(&stats[1152 + c], e);
    }
}

// ---------------- Kernel 2: BN coefficients ----------------
__global__ void bn_coeffs_k(float* __restrict__ stats,
                            const float* __restrict__ gL, const float* __restrict__ bL,
                            const float* __restrict__ gS, const float* __restrict__ bS)
{
    int c = threadIdx.x;
    if (c < CC) {
        const float inv_n = 1.0f / (float)NHW;
        float mL = stats[c] * inv_n;
        float vL = stats[384 + c] * inv_n - mL * mL;
        float aL = rsqrtf(vL + 1e-5f) * gL[c];
        float mS = stats[768 + c] * inv_n;
        float vS = stats[1152 + c] * inv_n - mS * mS;
        float aS = rsqrtf(vS + 1e-5f) * gS[c];
        stats[1536 + c] = aL;
        stats[1920 + c] = aS;
        stats[2304 + c] = bL[c] + bS[c] - mL * aL - mS * aS;
    }
}

// ---------------- Kernel 3: 5x5 conv + fused affine epilogue ----------------
__global__ __launch_bounds__(256) void fuse_small_k(
    const float* __restrict__ x, const float* __restrict__ wS,
    const __hip_bfloat16* __restrict__ yL, const float* __restrict__ stats,
    float* __restrict__ out)
{
    __shared__ float in_s[60 * ST3]; // 14640 B

    const int bid = blockIdx.x;
    const int c   = bid % CC;
    const int tid = threadIdx.x;

    const float* __restrict__ w2 = wS + c * 25;  // uniform -> SGPR

    for (int i = tid; i < 60 * ST3; i += 256) in_s[i] = 0.f;
    __syncthreads();

    const float4* xp = (const float4*)(x + (size_t)bid * PLANE);
    for (int t = tid; t < PLANE / 4; t += 256) {
        int r  = t / (WW / 4);
        int c4 = (t % (WW / 4)) * 4;
        float4 v = xp[t];
        float* dst = &in_s[(r + 2) * ST3 + 2 + c4];
        dst[0] = v.x; dst[1] = v.y; dst[2] = v.z; dst[3] = v.w;
    }
    __syncthreads();

    const float aL  = stats[1536 + c];
    const float aS  = stats[1920 + c];
    const float cst = stats[2304 + c];
    const __hip_bfloat16* yp = yL + (size_t)bid * PLANE;
    float* op = out + (size_t)bid * PLANE;

    for (int idx = tid; idx < PLANE; idx += 256) {
        int yy = idx / WW;
        int xx = idx - yy * WW;
        float s = 0.f;
        #pragma unroll
        for (int ky = 0; ky < 5; ++ky) {
            #pragma unroll
            for (int kx = 0; kx < 5; ++kx)
                s = fmaf(in_s[(yy + ky) * ST3 + xx + kx], w2[ky * 5 + kx], s);
        }
        op[idx] = fmaf(aL, __bfloat162float(yp[idx]), fmaf(aS, s, cst));
    }
}

extern "C" void kernel_launch(void* const* d_in, const int* in_sizes, int n_in,
                              void* d_out, int out_size, void* d_ws, size_t ws_size,
                              hipStream_t stream) {
    const float* x  = (const float*)d_in[0];
    const float* wL = (const float*)d_in[1];
    const float* gL = (const float*)d_in[2];
    const float* bL = (const float*)d_in[3];
    const float* wS = (const float*)d_in[4];
    const float* gS = (const float*)d_in[5];
    const float* bS = (const float*)d_in[6];
    float* out = (float*)d_out;

    __hip_bfloat16* yLbuf = (__hip_bfloat16*)d_ws;
    const size_t yl_bytes = (size_t)BB * CC * PLANE * sizeof(__hip_bfloat16); // 38.5 MB
    float* stats = (float*)((char*)d_ws + yl_bytes);

    hipMemsetAsync(stats, 0, 7 * CC * sizeof(float), stream); // sums + coeffs region

    conv_large_k<<<BB * CC, 256, 0, stream>>>(x, wL, wS, yLbuf, stats);
    bn_coeffs_k<<<1, CC, 0, stream>>>(stats, gL, bL, gS, bS);
    fuse_small_k<<<BB * CC, 256, 0, stream>>>(x, wS, yLbuf, stats, out);
}

// Round 4
// 577.441 us; speedup vs baseline: 1.2332x; 1.2332x over previous
//
#include <hip/hip_runtime.h>
#include <hip/hip_bf16.h>

#define BB 16
#define CC 384
#define HH 56
#define WW 56
#define PLANE (HH*WW)
#define NHW (BB*PLANE)
// Transposed (column-major) LDS: in_t[col*ST + row], 86 cols x 86 rows padded.
// ST=94: even -> b64 reads 8B-aligned (y0 even); 94 mod 32 = 30 -> 16
// consecutive lanes hit 16 distinct bank pairs -> conflict-free column reads.
#define ST 94
#define NCOL 86           // 15 + 56 + 15
#define LDS_WORDS (NCOL*ST)   // 8084
#define ST3 61            // kernel3 LDS stride (odd)

// ---------------- Kernel 1: 31x31 depthwise conv + stats (+5x5 stats) ----------------
// Streaming structure: thread = one output column, 14 output rows.
// Holds only acc[14] + one float2 -> ~25 VGPRs live; weights are
// loop-uniform -> SGPR broadcast. Nothing for the allocator to spill.
__global__ __launch_bounds__(256) void conv_large_k(
    const float* __restrict__ x, const float* __restrict__ wL,
    const float* __restrict__ wS,
    __hip_bfloat16* __restrict__ yL, float* __restrict__ stats)
{
    __shared__ __align__(16) float in_t[LDS_WORDS];  // 32336 B
    __shared__ float red_s[16];

    const int bid = blockIdx.x;
    const int c   = bid % CC;
    const int tid = threadIdx.x;

    const float* __restrict__ wrow = wL + c * 961;  // uniform -> s_load
    const float* __restrict__ w2   = wS + c * 25;

    // zero LDS (8084 words; do 8084 = 2021 float4)
    for (int i = tid * 4; i < LDS_WORDS; i += 256 * 4) {
        if (i + 4 <= LDS_WORDS) *(float4*)&in_t[i] = make_float4(0.f,0.f,0.f,0.f);
        else { for (int q = i; q < LDS_WORDS; ++q) in_t[q] = 0.f; }
    }
    __syncthreads();

    // stage plane transposed: global row-major float4 -> 4 column-major scalars
    const float4* xp = (const float4*)(x + (size_t)bid * PLANE);
    for (int t = tid; t < PLANE / 4; t += 256) {
        int r  = t / (WW / 4);        // row 0..55
        int c4 = (t % (WW / 4)) * 4;  // col 0..52
        float4 v = xp[t];
        in_t[(c4 + 15) * ST + (r + 15)] = v.x;
        in_t[(c4 + 16) * ST + (r + 15)] = v.y;
        in_t[(c4 + 17) * ST + (r + 15)] = v.z;
        in_t[(c4 + 18) * ST + (r + 15)] = v.w;
    }
    __syncthreads();

    const int xcol = tid & 63;   // output column (active < 56)
    const int g    = tid >> 6;   // row group 0..3
    const int y0   = g * 14;     // even -> b64 alignment holds

    float sL = 0.f, sL2 = 0.f, sS = 0.f, sS2 = 0.f;

    float acc[14];
    #pragma unroll
    for (int i = 0; i < 14; ++i) acc[i] = 0.f;
    float accS[14];
    #pragma unroll
    for (int i = 0; i < 14; ++i) accS[i] = 0.f;

    if (xcol < WW) {
        // ---- large conv: stream 44 rows per kx as 22 x ds_read_b64 ----
        #pragma unroll 1
        for (int kx = 0; kx < 31; ++kx) {
            const float* colp = &in_t[(xcol + kx) * ST + y0]; // padded rows y0..y0+43
            const float* wcol = wrow + kx;                    // w[ky*31 + kx]
            #pragma unroll
            for (int t = 0; t < 22; ++t) {
                float2 v = *(const float2*)&colp[2 * t];
                #pragma unroll
                for (int q = 0; q < 2; ++q) {
                    const int r = 2 * t + q;                  // padded row y0+r = global y0+r-15
                    const float val = q ? v.y : v.x;
                    #pragma unroll
                    for (int i = 0; i < 14; ++i) {
                        const int ky = r - i;                 // compile-time per (t,q,i)
                        if (ky >= 0 && ky <= 30)
                            acc[i] = fmaf(val, wcol[ky * 31], acc[i]);
                    }
                }
            }
        }

        // ---- small conv (stats only; recomputed in kernel 3) ----
        #pragma unroll 1
        for (int kx2 = 0; kx2 < 5; ++kx2) {
            const float* colp = &in_t[(xcol + kx2 + 13) * ST + y0 + 13]; // rows y0-2..y0+15
            const float* wcol = w2 + kx2;
            #pragma unroll
            for (int r2 = 0; r2 < 18; ++r2) {
                const float val = colp[r2];
                #pragma unroll
                for (int i = 0; i < 14; ++i) {
                    const int ky = r2 - i;
                    if (ky >= 0 && ky <= 4)
                        accS[i] = fmaf(val, wcol[ky * 5], accS[i]);
                }
            }
        }

        // ---- store yL (bf16, lane-coalesced) + accumulate stats ----
        __hip_bfloat16* yp = yL + (size_t)bid * PLANE + xcol;
        #pragma unroll
        for (int i = 0; i < 14; ++i) {
            float v = acc[i];
            sL += v; sL2 += v * v;
            yp[(y0 + i) * WW] = __float2bfloat16(v);
            float v2 = accS[i];
            sS += v2; sS2 += v2 * v2;
        }
    }

    // ---- block reduce 4 stats -> atomics ----
    #pragma unroll
    for (int off = 32; off > 0; off >>= 1) {
        sL  += __shfl_down(sL,  off);
        sL2 += __shfl_down(sL2, off);
        sS  += __shfl_down(sS,  off);
        sS2 += __shfl_down(sS2, off);
    }
    const int wid  = tid >> 6;
    const int lane = tid & 63;
    if (lane == 0) {
        red_s[wid * 4 + 0] = sL;  red_s[wid * 4 + 1] = sL2;
        red_s[wid * 4 + 2] = sS;  red_s[wid * 4 + 3] = sS2;
    }
    __syncthreads();
    if (tid == 0) {
        float a = 0.f, b = 0.f, d = 0.f, e = 0.f;
        #pragma unroll
        for (int w2i = 0; w2i < 4; ++w2i) {
            a += red_s[w2i * 4 + 0]; b += red_s[w2i * 4 + 1];
            d += red_s[w2i * 4 + 2]; e += red_s[w2i * 4 + 3];
        }
        atomicAdd(&stats[c],        a);
        atomicAdd(&stats[384 + c],  b);
        atomicAdd(&stats[768 + c],  d);
        atomicAdd(&stats[1152 + c], e);
    }
}

// ---------------- Kernel 2: BN coefficients ----------------
__global__ void bn_coeffs_k(float* __restrict__ stats,
                            const float* __restrict__ gL, const float* __restrict__ bL,
                            const float* __restrict__ gS, const float* __restrict__ bS)
{
    int c = threadIdx.x;
    if (c < CC) {
        const float inv_n = 1.0f / (float)NHW;
        float mL = stats[c] * inv_n;
        float vL = stats[384 + c] * inv_n - mL * mL;
        float aL = rsqrtf(vL + 1e-5f) * gL[c];
        float mS = stats[768 + c] * inv_n;
        float vS = stats[1152 + c] * inv_n - mS * mS;
        float aS = rsqrtf(vS + 1e-5f) * gS[c];
        stats[1536 + c] = aL;
        stats[1920 + c] = aS;
        stats[2304 + c] = bL[c] + bS[c] - mL * aL - mS * aS;
    }
}

// ---------------- Kernel 3: 5x5 conv + fused affine epilogue ----------------
__global__ __launch_bounds__(256) void fuse_small_k(
    const float* __restrict__ x, const float* __restrict__ wS,
    const __hip_bfloat16* __restrict__ yL, const float* __restrict__ stats,
    float* __restrict__ out)
{
    __shared__ float in_s[60 * ST3]; // 14640 B

    const int bid = blockIdx.x;
    const int c   = bid % CC;
    const int tid = threadIdx.x;

    const float* __restrict__ w2 = wS + c * 25;  // uniform -> SGPR

    for (int i = tid; i < 60 * ST3; i += 256) in_s[i] = 0.f;
    __syncthreads();

    const float4* xp = (const float4*)(x + (size_t)bid * PLANE);
    for (int t = tid; t < PLANE / 4; t += 256) {
        int r  = t / (WW / 4);
        int c4 = (t % (WW / 4)) * 4;
        float4 v = xp[t];
        float* dst = &in_s[(r + 2) * ST3 + 2 + c4];
        dst[0] = v.x; dst[1] = v.y; dst[2] = v.z; dst[3] = v.w;
    }
    __syncthreads();

    const float aL  = stats[1536 + c];
    const float aS  = stats[1920 + c];
    const float cst = stats[2304 + c];
    const __hip_bfloat16* yp = yL + (size_t)bid * PLANE;
    float* op = out + (size_t)bid * PLANE;

    for (int idx = tid; idx < PLANE; idx += 256) {
        int yy = idx / WW;
        int xx = idx - yy * WW;
        float s = 0.f;
        #pragma unroll
        for (int ky = 0; ky < 5; ++ky) {
            #pragma unroll
            for (int kx = 0; kx < 5; ++kx)
                s = fmaf(in_s[(yy + ky) * ST3 + xx + kx], w2[ky * 5 + kx], s);
        }
        op[idx] = fmaf(aL, __bfloat162float(yp[idx]), fmaf(aS, s, cst));
    }
}

extern "C" void kernel_launch(void* const* d_in, const int* in_sizes, int n_in,
                              void* d_out, int out_size, void* d_ws, size_t ws_size,
                              hipStream_t stream) {
    const float* x  = (const float*)d_in[0];
    const float* wL = (const float*)d_in[1];
    const float* gL = (const float*)d_in[2];
    const float* bL = (const float*)d_in[3];
    const float* wS = (const float*)d_in[4];
    const float* gS = (const float*)d_in[5];
    const float* bS = (const float*)d_in[6];
    float* out = (float*)d_out;

    __hip_bfloat16* yLbuf = (__hip_bfloat16*)d_ws;
    const size_t yl_bytes = (size_t)BB * CC * PLANE * sizeof(__hip_bfloat16); // 38.5 MB
    float* stats = (float*)((char*)d_ws + yl_bytes);

    hipMemsetAsync(stats, 0, 7 * CC * sizeof(float), stream); // sums + coeffs region

    conv_large_k<<<BB * CC, 256, 0, stream>>>(x, wL, wS, yLbuf, stats);
    bn_coeffs_k<<<1, CC, 0, stream>>>(stats, gL, bL, gS, bS);
    fuse_small_k<<<BB * CC, 256, 0, stream>>>(x, wS, yLbuf, stats, out);
}

// Round 5
// 569.340 us; speedup vs baseline: 1.2507x; 1.0142x over previous
//
#include <hip/hip_runtime.h>
#include <hip/hip_bf16.h>

#define BB 16
#define CC 384
#define HH 56
#define WW 56
#define PLANE (HH*WW)
#define NHW (BB*PLANE)
// Column-major LDS: in_t[col*ST + row]. ST=95 (odd): lane stride 95 = -1
// (mod 32) -> 32 distinct banks, 2 lanes/bank = free. Round-4's ST=94 (even,
// -2 mod 32) gave 4-way conflicts on every column read (measured 1990
// conflict-cyc/wave = exactly 682 reads x 3 phases).
#define ST 95
#define NCOL 86               // 15 + 56 + 15
#define LDS_WORDS 8172        // ceil(86*95 = 8170 to multiple of 4)
#define ST3 61                // kernel3 LDS stride (odd)

// ---------------- Kernel 1: 31x31 depthwise conv + stats (+5x5 stats) ----------------
// thread = (output column = lane, row-group of 14). acc[14]+accS[14] ~ 40 VGPR.
// Column reads: ds_read2_b32 pairs, conflict-free at odd ST.
// Staging: lane = column -> coalesced global dword reads, conflict-free ds writes.
__global__ __launch_bounds__(256) void conv_large_k(
    const float* __restrict__ x, const float* __restrict__ wL,
    const float* __restrict__ wS,
    __hip_bfloat16* __restrict__ yL, float* __restrict__ stats)
{
    __shared__ __align__(16) float in_t[LDS_WORDS];  // 32688 B
    __shared__ float red_s[16];

    const int bid = blockIdx.x;
    const int c   = bid % CC;
    const int tid = threadIdx.x;

    const float* __restrict__ wrow = wL + c * 961;  // uniform -> s_load
    const float* __restrict__ w2   = wS + c * 25;

    // zero LDS (halo regions must be 0; center overwritten below)
    for (int i = tid * 4; i < LDS_WORDS; i += 256 * 4)
        *(float4*)&in_t[i] = make_float4(0.f, 0.f, 0.f, 0.f);
    __syncthreads();

    const int xcol = tid & 63;   // column (active < 56)
    const int g    = tid >> 6;   // row group 0..3
    const int y0   = g * 14;

    // stage transposed: lane = column -> global reads stride-1 coalesced,
    // ds_write lane stride ST=95 = -1 mod 32 -> conflict-free
    if (xcol < WW) {
        const float* xc = x + (size_t)bid * PLANE + xcol;
        float* dcol = &in_t[(xcol + 15) * ST + 15];
        #pragma unroll
        for (int k = 0; k < 14; ++k) {
            int r = y0 + k;
            dcol[r] = xc[r * WW];
        }
    }
    __syncthreads();

    float sL = 0.f, sL2 = 0.f, sS = 0.f, sS2 = 0.f;

    float acc[14];
    #pragma unroll
    for (int i = 0; i < 14; ++i) acc[i] = 0.f;
    float accS[14];
    #pragma unroll
    for (int i = 0; i < 14; ++i) accS[i] = 0.f;

    if (xcol < WW) {
        // ---- large conv: stream 44 rows per kx as 22 x ds_read2_b32 ----
        #pragma unroll 1
        for (int kx = 0; kx < 31; ++kx) {
            const float* colp = &in_t[(xcol + kx) * ST + y0]; // padded rows y0..y0+43
            const float* wcol = wrow + kx;                    // w[ky*31 + kx]
            #pragma unroll
            for (int t = 0; t < 22; ++t) {
                float vx = colp[2 * t];      // merge -> ds_read2_b32
                float vy = colp[2 * t + 1];
                #pragma unroll
                for (int q = 0; q < 2; ++q) {
                    const int r = 2 * t + q;                  // padded row y0+r
                    const float val = q ? vy : vx;
                    #pragma unroll
                    for (int i = 0; i < 14; ++i) {
                        const int ky = r - i;                 // compile-time per (t,q,i)
                        if (ky >= 0 && ky <= 30)
                            acc[i] = fmaf(val, wcol[ky * 31], acc[i]);
                    }
                }
            }
        }

        // ---- small conv (stats only; recomputed in kernel 3) ----
        #pragma unroll 1
        for (int kx2 = 0; kx2 < 5; ++kx2) {
            const float* colp = &in_t[(xcol + kx2 + 13) * ST + y0 + 13]; // rows y0-2..y0+15
            const float* wcol = w2 + kx2;
            #pragma unroll
            for (int r2 = 0; r2 < 18; ++r2) {
                const float val = colp[r2];
                #pragma unroll
                for (int i = 0; i < 14; ++i) {
                    const int ky = r2 - i;
                    if (ky >= 0 && ky <= 4)
                        accS[i] = fmaf(val, wcol[ky * 5], accS[i]);
                }
            }
        }

        // ---- store yL (bf16, lane-coalesced) + accumulate stats ----
        __hip_bfloat16* yp = yL + (size_t)bid * PLANE + xcol;
        #pragma unroll
        for (int i = 0; i < 14; ++i) {
            float v = acc[i];
            sL += v; sL2 += v * v;
            yp[(y0 + i) * WW] = __float2bfloat16(v);
            float v2 = accS[i];
            sS += v2; sS2 += v2 * v2;
        }
    }

    // ---- block reduce 4 stats -> atomics ----
    #pragma unroll
    for (int off = 32; off > 0; off >>= 1) {
        sL  += __shfl_down(sL,  off);
        sL2 += __shfl_down(sL2, off);
        sS  += __shfl_down(sS,  off);
        sS2 += __shfl_down(sS2, off);
    }
    const int wid  = tid >> 6;
    const int lane = tid & 63;
    if (lane == 0) {
        red_s[wid * 4 + 0] = sL;  red_s[wid * 4 + 1] = sL2;
        red_s[wid * 4 + 2] = sS;  red_s[wid * 4 + 3] = sS2;
    }
    __syncthreads();
    if (tid == 0) {
        float a = 0.f, b = 0.f, d = 0.f, e = 0.f;
        #pragma unroll
        for (int w2i = 0; w2i < 4; ++w2i) {
            a += red_s[w2i * 4 + 0]; b += red_s[w2i * 4 + 1];
            d += red_s[w2i * 4 + 2]; e += red_s[w2i * 4 + 3];
        }
        atomicAdd(&stats[c],        a);
        atomicAdd(&stats[384 + c],  b);
        atomicAdd(&stats[768 + c],  d);
        atomicAdd(&stats[1152 + c], e);
    }
}

// ---------------- Kernel 2: 5x5 conv + BN coeffs + fused affine epilogue ----------------
__global__ __launch_bounds__(256) void fuse_small_k(
    const float* __restrict__ x, const float* __restrict__ wS,
    const __hip_bfloat16* __restrict__ yL, const float* __restrict__ stats,
    const float* __restrict__ gL, const float* __restrict__ bL,
    const float* __restrict__ gS, const float* __restrict__ bS,
    float* __restrict__ out)
{
    __shared__ float in_s[60 * ST3]; // 14640 B

    const int bid = blockIdx.x;
    const int c   = bid % CC;
    const int tid = threadIdx.x;

    const float* __restrict__ w2 = wS + c * 25;  // uniform -> SGPR

    for (int i = tid; i < 60 * ST3; i += 256) in_s[i] = 0.f;
    __syncthreads();

    const float4* xp = (const float4*)(x + (size_t)bid * PLANE);
    for (int t = tid; t < PLANE / 4; t += 256) {
        int r  = t / (WW / 4);
        int c4 = (t % (WW / 4)) * 4;
        float4 v = xp[t];
        float* dst = &in_s[(r + 2) * ST3 + 2 + c4];
        dst[0] = v.x; dst[1] = v.y; dst[2] = v.z; dst[3] = v.w;
    }
    __syncthreads();

    // BN coefficients (per-thread redundant; ~10 cycles, uniform loads)
    const float inv_n = 1.0f / (float)NHW;
    float mL = stats[c]         * inv_n;
    float vL = stats[384 + c]   * inv_n - mL * mL;
    float aL = rsqrtf(vL + 1e-5f) * gL[c];
    float mS = stats[768 + c]   * inv_n;
    float vS = stats[1152 + c]  * inv_n - mS * mS;
    float aS = rsqrtf(vS + 1e-5f) * gS[c];
    float cst = bL[c] + bS[c] - mL * aL - mS * aS;

    const __hip_bfloat16* yp = yL + (size_t)bid * PLANE;
    float* op = out + (size_t)bid * PLANE;

    for (int idx = tid; idx < PLANE; idx += 256) {
        int yy = idx / WW;
        int xx = idx - yy * WW;
        float s = 0.f;
        #pragma unroll
        for (int ky = 0; ky < 5; ++ky) {
            #pragma unroll
            for (int kx = 0; kx < 5; ++kx)
                s = fmaf(in_s[(yy + ky) * ST3 + xx + kx], w2[ky * 5 + kx], s);
        }
        op[idx] = fmaf(aL, __bfloat162float(yp[idx]), fmaf(aS, s, cst));
    }
}

extern "C" void kernel_launch(void* const* d_in, const int* in_sizes, int n_in,
                              void* d_out, int out_size, void* d_ws, size_t ws_size,
                              hipStream_t stream) {
    const float* x  = (const float*)d_in[0];
    const float* wL = (const float*)d_in[1];
    const float* gL = (const float*)d_in[2];
    const float* bL = (const float*)d_in[3];
    const float* wS = (const float*)d_in[4];
    const float* gS = (const float*)d_in[5];
    const float* bS = (const float*)d_in[6];
    float* out = (float*)d_out;

    __hip_bfloat16* yLbuf = (__hip_bfloat16*)d_ws;
    const size_t yl_bytes = (size_t)BB * CC * PLANE * sizeof(__hip_bfloat16); // 38.5 MB
    float* stats = (float*)((char*)d_ws + yl_bytes);

    hipMemsetAsync(stats, 0, 4 * CC * sizeof(float), stream); // raw sums

    conv_large_k<<<BB * CC, 256, 0, stream>>>(x, wL, wS, yLbuf, stats);
    fuse_small_k<<<BB * CC, 256, 0, stream>>>(x, wS, yLbuf, stats, gL, bL, gS, bS, out);
}